// Round 1
// baseline (1867.072 us; speedup 1.0000x reference)
//
#include <hip/hip_runtime.h>

// ---------------------------------------------------------------------------
// GNN_20237885899323: 2-layer GCN + mean-pool + MLP head, all fp32.
//   h0 = relu(x @ w_node + b_node)                  [N,32]
//   h1 = relu(gcnconv(h0, w1, b1))                  [N,64]
//   h2 = relu(gcnconv(h1, w2, b2))                  [N,64]
//   pooled = segment_mean(h2, batch)                [G,64]
//   out = relu(pooled@wf1+bf1) @ wf2 + bf2          [G,1]
// gcnconv: deg[v] = indeg(v)+1 (self loop); dis = rsqrt(deg);
//   acc[v] = xw[v]*dis[v]^2 + sum_{e:dst=v} xw[src]*dis[src]*dis[v]; +b
// ---------------------------------------------------------------------------

__global__ void k_deg(const int* __restrict__ dst, float* __restrict__ deg, int E) {
    int i = blockIdx.x * blockDim.x + threadIdx.x;
    if (i < E) atomicAdd(&deg[dst[i]], 1.0f);
}

__global__ void k_dis(float* __restrict__ deg, int N) {
    int i = blockIdx.x * blockDim.x + threadIdx.x;
    if (i < N) deg[i] = rsqrtf(deg[i] + 1.0f);  // +1 self loop; deg>=1 always
}

// h0 = relu(x @ w_node + b_node); x:[N,2], w:[2,32]
__global__ void k_node_init(const float* __restrict__ x, const float* __restrict__ w,
                            const float* __restrict__ b, float* __restrict__ h0, int N) {
    int tid = blockIdx.x * blockDim.x + threadIdx.x;
    if (tid >= N * 32) return;
    int n = tid >> 5, f = tid & 31;
    float v = x[2 * n] * w[f] + x[2 * n + 1] * w[32 + f] + b[f];
    h0[tid] = v > 0.f ? v : 0.f;
}

// xw = h @ w  (h:[N,K], w:[K,64]); acc = xw * dis^2  (self-loop init)
template <int K>
__global__ void k_xw(const float* __restrict__ h, const float* __restrict__ w,
                     const float* __restrict__ dis, float* __restrict__ xw,
                     float* __restrict__ acc, int N) {
    int tid = blockIdx.x * blockDim.x + threadIdx.x;
    if (tid >= N * 64) return;
    int n = tid >> 6, f = tid & 63;
    const float* hr = h + n * K;
    float s = 0.f;
#pragma unroll
    for (int k = 0; k < K; ++k) s += hr[k] * w[k * 64 + f];
    xw[tid] = s;
    float d = dis[n];
    acc[tid] = s * d * d;
}

// one wave (64 lanes) per edge: acc[dst][f] += xw[src][f] * dis[src]*dis[dst]
__global__ void k_edge(const int* __restrict__ ei, const float* __restrict__ xw,
                       const float* __restrict__ dis, float* __restrict__ acc, int E) {
    int tid = blockIdx.x * blockDim.x + threadIdx.x;
    int eid = tid >> 6, f = tid & 63;
    if (eid >= E) return;
    int s = ei[eid];
    int d = ei[E + eid];
    float norm = dis[s] * dis[d];
    atomicAdd(&acc[d * 64 + f], xw[s * 64 + f] * norm);
}

// h = relu(acc + b)
__global__ void k_fin(const float* __restrict__ acc, const float* __restrict__ b,
                      float* __restrict__ h, int total) {
    int tid = blockIdx.x * blockDim.x + threadIdx.x;
    if (tid >= total) return;
    float v = acc[tid] + b[tid & 63];
    h[tid] = v > 0.f ? v : 0.f;
}

// segment-sum into per-graph sums + counts
__global__ void k_pool(const float* __restrict__ h, const int* __restrict__ batch,
                       float* __restrict__ sums, float* __restrict__ cnt, int N) {
    int tid = blockIdx.x * blockDim.x + threadIdx.x;
    int n = tid >> 6, f = tid & 63;
    if (n >= N) return;
    int g = batch[n];
    atomicAdd(&sums[g * 64 + f], h[tid]);
    if (f == 0) atomicAdd(&cnt[g], 1.0f);
}

// per-graph head: pooled -> relu(pooled@wf1+bf1) -> @wf2+bf2
__global__ void k_head(const float* __restrict__ sums, const float* __restrict__ cnt,
                       const float* __restrict__ wf1, const float* __restrict__ bf1,
                       const float* __restrict__ wf2, const float* __restrict__ bf2,
                       float* __restrict__ out) {
    int g = blockIdx.x;
    int t = threadIdx.x;  // 64 threads
    __shared__ float pooled[64];
    __shared__ float gv[32];
    float c = cnt[g];
    c = c > 1.f ? c : 1.f;
    pooled[t] = sums[g * 64 + t] / c;
    __syncthreads();
    if (t < 32) {
        float s = bf1[t];
#pragma unroll
        for (int k = 0; k < 64; ++k) s += pooled[k] * wf1[k * 32 + t];
        gv[t] = s > 0.f ? s : 0.f;
    }
    __syncthreads();
    if (t == 0) {
        float s = bf2[0];
#pragma unroll
        for (int j = 0; j < 32; ++j) s += gv[j] * wf2[j];
        out[g] = s;
    }
}

extern "C" void kernel_launch(void* const* d_in, const int* in_sizes, int n_in,
                              void* d_out, int out_size, void* d_ws, size_t ws_size,
                              hipStream_t stream) {
    const float* x      = (const float*)d_in[0];
    // d_in[1] edge_attr: unused downstream in reference
    const int*   ei     = (const int*)d_in[2];
    const int*   batch  = (const int*)d_in[3];
    const float* w_node = (const float*)d_in[4];
    const float* b_node = (const float*)d_in[5];
    // d_in[6], d_in[7]: w_edge/b_edge unused
    const float* w1  = (const float*)d_in[8];
    const float* b1  = (const float*)d_in[9];
    const float* w2  = (const float*)d_in[10];
    const float* b2  = (const float*)d_in[11];
    const float* wf1 = (const float*)d_in[12];
    const float* bf1 = (const float*)d_in[13];
    const float* wf2 = (const float*)d_in[14];
    const float* bf2 = (const float*)d_in[15];
    float* out = (float*)d_out;

    const int N = in_sizes[0] / 2;       // 100000
    const int E = in_sizes[2] / 2;       // 3200000
    const int G = out_size;              // 1024

    // workspace layout (256B-aligned chunks)
    auto align256 = [](size_t v) { return (v + 255) & ~(size_t)255; };
    char* ws = (char*)d_ws;
    size_t off = 0;
    float* dis  = (float*)(ws + off); off += align256((size_t)N * 4);
    float* hA   = (float*)(ws + off); off += align256((size_t)N * 64 * 4);
    float* hB   = (float*)(ws + off); off += align256((size_t)N * 64 * 4);  // xw
    float* hC   = (float*)(ws + off); off += align256((size_t)N * 64 * 4);  // acc
    float* sums = (float*)(ws + off); off += align256((size_t)G * 64 * 4);
    float* cnt  = (float*)(ws + off); off += align256((size_t)G * 4);

    // zero what atomics accumulate into (ws is poisoned, not re-poisoned)
    hipMemsetAsync(dis, 0, (size_t)N * 4, stream);
    hipMemsetAsync(sums, 0, (size_t)G * 64 * 4, stream);
    hipMemsetAsync(cnt, 0, (size_t)G * 4, stream);

    const int B = 256;
    k_deg<<<(E + B - 1) / B, B, 0, stream>>>(ei + E, dis, E);   // dst row
    k_dis<<<(N + B - 1) / B, B, 0, stream>>>(dis, N);
    k_node_init<<<(N * 32 + B - 1) / B, B, 0, stream>>>(x, w_node, b_node, hA, N);

    // layer 1: K=32
    k_xw<32><<<(N * 64 + B - 1) / B, B, 0, stream>>>(hA, w1, dis, hB, hC, N);
    {
        long long threads = (long long)E * 64;
        k_edge<<<(int)((threads + B - 1) / B), B, 0, stream>>>(ei, hB, dis, hC, E);
    }
    k_fin<<<(N * 64 + B - 1) / B, B, 0, stream>>>(hC, b1, hA, N * 64);

    // layer 2: K=64
    k_xw<64><<<(N * 64 + B - 1) / B, B, 0, stream>>>(hA, w2, dis, hB, hC, N);
    {
        long long threads = (long long)E * 64;
        k_edge<<<(int)((threads + B - 1) / B), B, 0, stream>>>(ei, hB, dis, hC, E);
    }
    k_fin<<<(N * 64 + B - 1) / B, B, 0, stream>>>(hC, b2, hA, N * 64);

    // pooling + head
    k_pool<<<(N * 64 + B - 1) / B, B, 0, stream>>>(hA, batch, sums, cnt, N);
    k_head<<<G, 64, 0, stream>>>(sums, cnt, wf1, bf1, wf2, bf2, out);
}

// Round 2
// 909.962 us; speedup vs baseline: 2.0518x; 2.0518x over previous
//
#include <hip/hip_runtime.h>

// ---------------------------------------------------------------------------
// GNN_20237885899323: 2-layer GCN + mean-pool + MLP head, all fp32.
// Round 2: replace per-edge fp32 atomics (819 MB atomic write traffic/layer,
// memory-side-atomic bound) with on-device CSR (dst-sorted) + one-wave-per-node
// register aggregation. Fuse dis scaling, bias+relu, and mean-pool epilogues.
// ---------------------------------------------------------------------------

// in-degree histogram (int)
__global__ void k_hist(const int* __restrict__ dst, int* __restrict__ degInt, int E) {
    int i = blockIdx.x * blockDim.x + threadIdx.x;
    if (i < E) atomicAdd(&degInt[dst[i]], 1);
}

// dis = rsqrt(deg + 1)  (+1 = self loop)
__global__ void k_dis(const int* __restrict__ degInt, float* __restrict__ dis, int N) {
    int i = blockIdx.x * blockDim.x + threadIdx.x;
    if (i < N) dis[i] = rsqrtf((float)degInt[i] + 1.0f);
}

// ---- exclusive scan of degInt -> rowPtr (3 kernels, 1024 elems/block) ----
#define SCAN_B 256
#define SCAN_E 4  // elements per thread -> 1024 per block

__global__ void k_scan1(const int* __restrict__ in, int* __restrict__ outLocal,
                        int* __restrict__ blockSums, int N) {
    __shared__ int sh[SCAN_B];
    int base = blockIdx.x * (SCAN_B * SCAN_E);
    int t = threadIdx.x;
    int v[SCAN_E];
    int sum = 0;
#pragma unroll
    for (int j = 0; j < SCAN_E; ++j) {
        int idx = base + t * SCAN_E + j;
        v[j] = (idx < N) ? in[idx] : 0;
        sum += v[j];
    }
    sh[t] = sum;
    __syncthreads();
    for (int off = 1; off < SCAN_B; off <<= 1) {
        int val = (t >= off) ? sh[t - off] : 0;
        __syncthreads();
        sh[t] += val;
        __syncthreads();
    }
    int excl = sh[t] - sum;  // exclusive prefix of this thread's chunk
    if (t == SCAN_B - 1) blockSums[blockIdx.x] = sh[t];
    int run = excl;
#pragma unroll
    for (int j = 0; j < SCAN_E; ++j) {
        int idx = base + t * SCAN_E + j;
        if (idx < N) outLocal[idx] = run;
        run += v[j];
    }
}

__global__ void k_scan2(int* __restrict__ blockSums, int nb) {
    __shared__ int sh[256];
    int t = threadIdx.x;
    int v = (t < nb) ? blockSums[t] : 0;
    sh[t] = v;
    __syncthreads();
    for (int off = 1; off < 256; off <<= 1) {
        int val = (t >= off) ? sh[t - off] : 0;
        __syncthreads();
        sh[t] += val;
        __syncthreads();
    }
    if (t < nb) blockSums[t] = sh[t] - v;  // exclusive
}

__global__ void k_scan3(int* __restrict__ rowPtr, int* __restrict__ fill,
                        const int* __restrict__ blockSums, const int* __restrict__ degInt,
                        int N) {
    int idx = blockIdx.x * blockDim.x + threadIdx.x;
    if (idx >= N) return;
    int v = rowPtr[idx] + blockSums[idx >> 10];  // 1024 elems per scan1 block
    rowPtr[idx] = v;
    fill[idx] = v;  // scatter cursor starts at segment begin
    if (idx == N - 1) rowPtr[N] = v + degInt[idx];  // == E
}

// bucket edges by dst: srcIdx[segment(dst)] = src
__global__ void k_scatter(const int* __restrict__ ei, int* __restrict__ fill,
                          int* __restrict__ srcIdx, int E) {
    int e = blockIdx.x * blockDim.x + threadIdx.x;
    if (e >= E) return;
    int s = ei[e];
    int d = ei[E + e];
    int pos = atomicAdd(&fill[d], 1);
    srcIdx[pos] = s;
}

// h0 = relu(x @ w_node + b_node); x:[N,2], w:[2,32]
__global__ void k_node_init(const float* __restrict__ x, const float* __restrict__ w,
                            const float* __restrict__ b, float* __restrict__ h0, int N) {
    int tid = blockIdx.x * blockDim.x + threadIdx.x;
    if (tid >= N * 32) return;
    int n = tid >> 5, f = tid & 31;
    float v = x[2 * n] * w[f] + x[2 * n + 1] * w[32 + f] + b[f];
    h0[tid] = v > 0.f ? v : 0.f;
}

// y = (h @ w) * dis[n]   (h:[N,K], w:[K,64])
template <int K>
__global__ void k_xw(const float* __restrict__ h, const float* __restrict__ w,
                     const float* __restrict__ dis, float* __restrict__ y, int N) {
    int tid = blockIdx.x * blockDim.x + threadIdx.x;
    if (tid >= N * 64) return;
    int n = tid >> 6, f = tid & 63;
    const float* hr = h + (size_t)n * K;
    float s = 0.f;
#pragma unroll
    for (int k = 0; k < K; ++k) s += hr[k] * w[k * 64 + f];
    y[tid] = s * dis[n];
}

// one wave per dst node: acc = y[v] + sum_{src in CSR[v]} y[src];
// out = relu(dis[v]*acc + b). POOL: atomically add into per-graph sums instead.
template <bool POOL>
__global__ void k_agg(const int* __restrict__ rowPtr, const int* __restrict__ srcIdx,
                      const float* __restrict__ y, const float* __restrict__ dis,
                      const float* __restrict__ b, float* __restrict__ hOut,
                      const int* __restrict__ batch, float* __restrict__ sums,
                      float* __restrict__ cnt, int N) {
    int wid = (blockIdx.x * blockDim.x + threadIdx.x) >> 6;  // node id
    int f = threadIdx.x & 63;
    if (wid >= N) return;
    int beg = rowPtr[wid], end = rowPtr[wid + 1];
    float acc = y[(size_t)wid * 64 + f];  // self loop (y already has dis[src])
    int i = beg;
    for (; i + 4 <= end; i += 4) {
        int s0 = srcIdx[i], s1 = srcIdx[i + 1], s2 = srcIdx[i + 2], s3 = srcIdx[i + 3];
        float a0 = y[(size_t)s0 * 64 + f];
        float a1 = y[(size_t)s1 * 64 + f];
        float a2 = y[(size_t)s2 * 64 + f];
        float a3 = y[(size_t)s3 * 64 + f];
        acc += a0;
        acc += a1;
        acc += a2;
        acc += a3;
    }
    for (; i < end; ++i) acc += y[(size_t)srcIdx[i] * 64 + f];
    float v = dis[wid] * acc + b[f];
    v = v > 0.f ? v : 0.f;
    if (!POOL) {
        hOut[(size_t)wid * 64 + f] = v;
    } else {
        int g = batch[wid];
        atomicAdd(&sums[g * 64 + f], v);
        if (f == 0) atomicAdd(&cnt[g], 1.0f);
    }
}

// per-graph head: pooled -> relu(pooled@wf1+bf1) -> @wf2+bf2
__global__ void k_head(const float* __restrict__ sums, const float* __restrict__ cnt,
                       const float* __restrict__ wf1, const float* __restrict__ bf1,
                       const float* __restrict__ wf2, const float* __restrict__ bf2,
                       float* __restrict__ out) {
    int g = blockIdx.x;
    int t = threadIdx.x;  // 64 threads
    __shared__ float pooled[64];
    __shared__ float gv[32];
    float c = cnt[g];
    c = c > 1.f ? c : 1.f;
    pooled[t] = sums[g * 64 + t] / c;
    __syncthreads();
    if (t < 32) {
        float s = bf1[t];
#pragma unroll
        for (int k = 0; k < 64; ++k) s += pooled[k] * wf1[k * 32 + t];
        gv[t] = s > 0.f ? s : 0.f;
    }
    __syncthreads();
    if (t == 0) {
        float s = bf2[0];
#pragma unroll
        for (int j = 0; j < 32; ++j) s += gv[j] * wf2[j];
        out[g] = s;
    }
}

extern "C" void kernel_launch(void* const* d_in, const int* in_sizes, int n_in,
                              void* d_out, int out_size, void* d_ws, size_t ws_size,
                              hipStream_t stream) {
    const float* x      = (const float*)d_in[0];
    const int*   ei     = (const int*)d_in[2];
    const int*   batch  = (const int*)d_in[3];
    const float* w_node = (const float*)d_in[4];
    const float* b_node = (const float*)d_in[5];
    const float* w1  = (const float*)d_in[8];
    const float* b1  = (const float*)d_in[9];
    const float* w2  = (const float*)d_in[10];
    const float* b2  = (const float*)d_in[11];
    const float* wf1 = (const float*)d_in[12];
    const float* bf1 = (const float*)d_in[13];
    const float* wf2 = (const float*)d_in[14];
    const float* bf2 = (const float*)d_in[15];
    float* out = (float*)d_out;

    const int N = in_sizes[0] / 2;  // 100000
    const int E = in_sizes[2] / 2;  // 3200000
    const int G = out_size;         // 1024

    auto align256 = [](size_t v) { return (v + 255) & ~(size_t)255; };
    char* ws = (char*)d_ws;
    size_t off = 0;
    int*   degInt  = (int*)(ws + off);   off += align256((size_t)N * 4);
    float* dis     = (float*)(ws + off); off += align256((size_t)N * 4);
    int*   rowPtr  = (int*)(ws + off);   off += align256((size_t)(N + 1) * 4);
    int*   fill    = (int*)(ws + off);   off += align256((size_t)N * 4);
    int*   bsums   = (int*)(ws + off);   off += align256((size_t)256 * 4);
    int*   srcIdx  = (int*)(ws + off);   off += align256((size_t)E * 4);
    float* hA      = (float*)(ws + off); off += align256((size_t)N * 64 * 4);
    float* y       = (float*)(ws + off); off += align256((size_t)N * 64 * 4);
    float* sums    = (float*)(ws + off); off += align256((size_t)G * 64 * 4);
    float* cnt     = (float*)(ws + off); off += align256((size_t)G * 4);

    // zero atomic accumulators (ws is poisoned, not re-poisoned between replays)
    hipMemsetAsync(degInt, 0, (size_t)N * 4, stream);
    hipMemsetAsync(sums, 0, (size_t)G * 64 * 4, stream);
    hipMemsetAsync(cnt, 0, (size_t)G * 4, stream);

    const int B = 256;
    const int nbScan = (N + SCAN_B * SCAN_E - 1) / (SCAN_B * SCAN_E);  // 98

    // ---- CSR build (once, reused by both layers) ----
    k_hist<<<(E + B - 1) / B, B, 0, stream>>>(ei + E, degInt, E);
    k_dis<<<(N + B - 1) / B, B, 0, stream>>>(degInt, dis, N);
    k_scan1<<<nbScan, SCAN_B, 0, stream>>>(degInt, rowPtr, bsums, N);
    k_scan2<<<1, 256, 0, stream>>>(bsums, nbScan);
    k_scan3<<<(N + B - 1) / B, B, 0, stream>>>(rowPtr, fill, bsums, degInt, N);
    k_scatter<<<(E + B - 1) / B, B, 0, stream>>>(ei, fill, srcIdx, E);

    // ---- node encoder ----
    k_node_init<<<(N * 32 + B - 1) / B, B, 0, stream>>>(x, w_node, b_node, hA, N);

    // ---- layer 1 (K=32) ----
    k_xw<32><<<(N * 64 + B - 1) / B, B, 0, stream>>>(hA, w1, dis, y, N);
    k_agg<false><<<(N * 64 + B - 1) / B, B, 0, stream>>>(rowPtr, srcIdx, y, dis, b1,
                                                         hA, nullptr, nullptr, nullptr, N);

    // ---- layer 2 (K=64) + fused mean-pool accumulate ----
    k_xw<64><<<(N * 64 + B - 1) / B, B, 0, stream>>>(hA, w2, dis, y, N);
    k_agg<true><<<(N * 64 + B - 1) / B, B, 0, stream>>>(rowPtr, srcIdx, y, dis, b2,
                                                        nullptr, batch, sums, cnt, N);

    // ---- head ----
    k_head<<<G, 64, 0, stream>>>(sums, cnt, wf1, bf1, wf2, bf2, out);
}

// Round 4
// 555.434 us; speedup vs baseline: 3.3615x; 1.6383x over previous
//
#include <hip/hip_runtime.h>

// ---------------------------------------------------------------------------
// GNN_20237885899323: 2-layer GCN + mean-pool + MLP head, all fp32.
// Round 4: round-3 structure (two-pass binned counting sort for CSR) with the
// signed-shift bug fixed: packed entries ((dst&255)<<24 | src) are UNSIGNED,
// read back with logical shift. Round-3 crash was hist[e>>24] with negative
// e (arithmetic shift sign-extension) -> LDS OOB -> abort.
// ---------------------------------------------------------------------------

#define NBMAX 512   // allocated buckets (actual NB = ceil(N/256) = 391)
#define BCAP 12288  // pairBuf capacity per bucket (expected ~8192 +- 90)
#define CAPL 10240  // LDS staging capacity in pass B (40 KB)

__global__ void k_initcur(int* __restrict__ bcur) {
    bcur[threadIdx.x] = threadIdx.x * BCAP;  // 512 threads
}

// pass A: bin edges by dst>>8 into pairBuf regions; entry = (dst&255)<<24 | src
__global__ void k_passA(const int* __restrict__ ei, int* __restrict__ bcur,
                        unsigned int* __restrict__ pairBuf, int E) {
    __shared__ int h[NBMAX];     // hist, then local cursor
    __shared__ int base[NBMAX];  // reserved global base per bucket
    const int T = 256, EPT = 32;
    int chunk = blockIdx.x * (T * EPT);
    int t = threadIdx.x;
    h[t] = 0; h[t + 256] = 0;
    __syncthreads();
    int nE = min(E - chunk, T * EPT);
    for (int i = t; i < nE; i += T)
        atomicAdd(&h[ei[E + chunk + i] >> 8], 1);
    __syncthreads();
    for (int bb = t; bb < NBMAX; bb += T) {
        int c = h[bb];
        base[bb] = c > 0 ? atomicAdd(&bcur[bb], c) : 0;
        h[bb] = 0;  // becomes local cursor
    }
    __syncthreads();
    for (int i = t; i < nE; i += T) {
        int s = ei[chunk + i];
        int d = ei[E + chunk + i];
        int bb = d >> 8;
        int pos = base[bb] + atomicAdd(&h[bb], 1);
        pairBuf[pos] = ((unsigned int)(d & 255) << 24) | (unsigned int)s;
    }
}

// bucket totals -> exclusive scan -> bucketBase; rowPtr[N] = E
__global__ void k_bucketScan(const int* __restrict__ bcur, int* __restrict__ bucketBase,
                             int* __restrict__ rowPtr, int N, int E, int NB) {
    __shared__ int sh[NBMAX];
    int t = threadIdx.x;  // 512
    int c = (t < NB) ? (bcur[t] - t * BCAP) : 0;
    sh[t] = c;
    __syncthreads();
    for (int off = 1; off < NBMAX; off <<= 1) {
        int v = (t >= off) ? sh[t - off] : 0;
        __syncthreads();
        sh[t] += v;
        __syncthreads();
    }
    bucketBase[t] = sh[t] - c;  // exclusive prefix
    if (t == 0) rowPtr[N] = E;
}

// pass B: per-bucket local counting sort; emits rowPtr, dis, srcIdx
__global__ void k_passB(const int* __restrict__ bcur, const int* __restrict__ bucketBase,
                        const unsigned int* __restrict__ pairBuf, int* __restrict__ rowPtr,
                        float* __restrict__ dis, int* __restrict__ srcIdx, int N) {
    __shared__ unsigned int eLds[CAPL];
    __shared__ int hist[256];
    __shared__ int scan[256];
    int b = blockIdx.x;
    int t = threadIdx.x;  // 256
    int count = bcur[b] - b * BCAP;
    int gbase = bucketBase[b];
    const unsigned int* src = pairBuf + (size_t)b * BCAP;
    hist[t] = 0;
    int nStage = min(count, CAPL);
    for (int i = t; i < nStage; i += 256) eLds[i] = src[i];
    __syncthreads();
    for (int i = t; i < nStage; i += 256) atomicAdd(&hist[eLds[i] >> 24], 1);
    for (int i = CAPL + t; i < count; i += 256) atomicAdd(&hist[src[i] >> 24], 1);
    __syncthreads();
    int c = hist[t];
    scan[t] = c;
    __syncthreads();
    for (int off = 1; off < 256; off <<= 1) {
        int v = (t >= off) ? scan[t - off] : 0;
        __syncthreads();
        scan[t] += v;
        __syncthreads();
    }
    int excl = scan[t] - c;
    int node = (b << 8) + t;
    if (node < N) {
        rowPtr[node] = gbase + excl;
        dis[node] = rsqrtf((float)c + 1.0f);  // +1 self loop
    }
    hist[t] = excl;  // reuse as cursor
    __syncthreads();
    for (int i = t; i < nStage; i += 256) {
        unsigned int e = eLds[i];
        int pos = atomicAdd(&hist[e >> 24], 1);
        srcIdx[gbase + pos] = (int)(e & 0xFFFFFFu);
    }
    for (int i = CAPL + t; i < count; i += 256) {
        unsigned int e = src[i];
        int pos = atomicAdd(&hist[e >> 24], 1);
        srcIdx[gbase + pos] = (int)(e & 0xFFFFFFu);
    }
}

// h0 = relu(x @ w_node + b_node); x:[N,2], w:[2,32]
__global__ void k_node_init(const float* __restrict__ x, const float* __restrict__ w,
                            const float* __restrict__ b, float* __restrict__ h0, int N) {
    int tid = blockIdx.x * blockDim.x + threadIdx.x;
    if (tid >= N * 32) return;
    int n = tid >> 5, f = tid & 31;
    float v = x[2 * n] * w[f] + x[2 * n + 1] * w[32 + f] + b[f];
    h0[tid] = v > 0.f ? v : 0.f;
}

// y = (h @ w) * dis[n]   (h:[N,K], w:[K,64])
template <int K>
__global__ void k_xw(const float* __restrict__ h, const float* __restrict__ w,
                     const float* __restrict__ dis, float* __restrict__ y, int N) {
    int tid = blockIdx.x * blockDim.x + threadIdx.x;
    if (tid >= N * 64) return;
    int n = tid >> 6, f = tid & 63;
    const float* hr = h + (size_t)n * K;
    float s = 0.f;
#pragma unroll
    for (int k = 0; k < K; ++k) s += hr[k] * w[k * 64 + f];
    y[tid] = s * dis[n];
}

// one wave per dst node: acc = y[v] + sum_{src in CSR[v]} y[src];
// out = relu(dis[v]*acc + b). POOL: atomically add into per-graph sums instead.
template <bool POOL>
__global__ void k_agg(const int* __restrict__ rowPtr, const int* __restrict__ srcIdx,
                      const float* __restrict__ y, const float* __restrict__ dis,
                      const float* __restrict__ b, float* __restrict__ hOut,
                      const int* __restrict__ batch, float* __restrict__ sums,
                      float* __restrict__ cnt, int N) {
    int wid = (blockIdx.x * blockDim.x + threadIdx.x) >> 6;  // node id
    int f = threadIdx.x & 63;
    if (wid >= N) return;
    int beg = rowPtr[wid], end = rowPtr[wid + 1];
    float acc0 = y[(size_t)wid * 64 + f];  // self loop (y already has dis[src])
    float acc1 = 0.f;
    int i = beg;
    for (; i + 8 <= end; i += 8) {
        int s0 = srcIdx[i],     s1 = srcIdx[i + 1], s2 = srcIdx[i + 2], s3 = srcIdx[i + 3];
        int s4 = srcIdx[i + 4], s5 = srcIdx[i + 5], s6 = srcIdx[i + 6], s7 = srcIdx[i + 7];
        float a0 = y[(size_t)s0 * 64 + f];
        float a1 = y[(size_t)s1 * 64 + f];
        float a2 = y[(size_t)s2 * 64 + f];
        float a3 = y[(size_t)s3 * 64 + f];
        float a4 = y[(size_t)s4 * 64 + f];
        float a5 = y[(size_t)s5 * 64 + f];
        float a6 = y[(size_t)s6 * 64 + f];
        float a7 = y[(size_t)s7 * 64 + f];
        acc0 += a0 + a2 + a4 + a6;
        acc1 += a1 + a3 + a5 + a7;
    }
    for (; i < end; ++i) acc0 += y[(size_t)srcIdx[i] * 64 + f];
    float v = dis[wid] * (acc0 + acc1) + b[f];
    v = v > 0.f ? v : 0.f;
    if (!POOL) {
        hOut[(size_t)wid * 64 + f] = v;
    } else {
        int g = batch[wid];
        atomicAdd(&sums[g * 64 + f], v);
        if (f == 0) atomicAdd(&cnt[g], 1.0f);
    }
}

// per-graph head: pooled -> relu(pooled@wf1+bf1) -> @wf2+bf2
__global__ void k_head(const float* __restrict__ sums, const float* __restrict__ cnt,
                       const float* __restrict__ wf1, const float* __restrict__ bf1,
                       const float* __restrict__ wf2, const float* __restrict__ bf2,
                       float* __restrict__ out) {
    int g = blockIdx.x;
    int t = threadIdx.x;  // 64 threads
    __shared__ float pooled[64];
    __shared__ float gv[32];
    float c = cnt[g];
    c = c > 1.f ? c : 1.f;
    pooled[t] = sums[g * 64 + t] / c;
    __syncthreads();
    if (t < 32) {
        float s = bf1[t];
#pragma unroll
        for (int k = 0; k < 64; ++k) s += pooled[k] * wf1[k * 32 + t];
        gv[t] = s > 0.f ? s : 0.f;
    }
    __syncthreads();
    if (t == 0) {
        float s = bf2[0];
#pragma unroll
        for (int j = 0; j < 32; ++j) s += gv[j] * wf2[j];
        out[g] = s;
    }
}

extern "C" void kernel_launch(void* const* d_in, const int* in_sizes, int n_in,
                              void* d_out, int out_size, void* d_ws, size_t ws_size,
                              hipStream_t stream) {
    const float* x      = (const float*)d_in[0];
    const int*   ei     = (const int*)d_in[2];
    const int*   batch  = (const int*)d_in[3];
    const float* w_node = (const float*)d_in[4];
    const float* b_node = (const float*)d_in[5];
    const float* w1  = (const float*)d_in[8];
    const float* b1  = (const float*)d_in[9];
    const float* w2  = (const float*)d_in[10];
    const float* b2  = (const float*)d_in[11];
    const float* wf1 = (const float*)d_in[12];
    const float* bf1 = (const float*)d_in[13];
    const float* wf2 = (const float*)d_in[14];
    const float* bf2 = (const float*)d_in[15];
    float* out = (float*)d_out;

    const int N = in_sizes[0] / 2;  // 100000
    const int E = in_sizes[2] / 2;  // 3200000
    const int G = out_size;         // 1024
    const int NB = (N + 255) >> 8;  // 391 buckets

    auto align256 = [](size_t v) { return (v + 255) & ~(size_t)255; };
    char* ws = (char*)d_ws;
    size_t off = 0;
    float* dis     = (float*)(ws + off); off += align256((size_t)N * 4);
    int*   rowPtr  = (int*)(ws + off);   off += align256((size_t)(N + 1) * 4);
    int*   bcur    = (int*)(ws + off);   off += align256((size_t)NBMAX * 4);
    int*   bbase   = (int*)(ws + off);   off += align256((size_t)NBMAX * 4);
    int*   srcIdx  = (int*)(ws + off);   off += align256((size_t)E * 4);
    float* hA      = (float*)(ws + off); off += align256((size_t)N * 64 * 4);
    float* y       = (float*)(ws + off); off += align256((size_t)N * 64 * 4);
    float* sums    = (float*)(ws + off); off += align256((size_t)G * 64 * 4);
    float* cnt     = (float*)(ws + off); off += align256((size_t)G * 4);
    // pairBuf aliases y: CSR build completes before k_xw writes y.
    // Max pairBuf use = NB*BCAP*4 = 391*12288*4 = 19.2 MB < 25.6 MB.
    unsigned int* pairBuf = (unsigned int*)y;

    hipMemsetAsync(sums, 0, (size_t)G * 64 * 4, stream);
    hipMemsetAsync(cnt, 0, (size_t)G * 4, stream);

    const int B = 256;

    // ---- CSR build ----
    k_initcur<<<1, NBMAX, 0, stream>>>(bcur);
    {
        int nblk = (E + B * 32 - 1) / (B * 32);  // 391
        k_passA<<<nblk, B, 0, stream>>>(ei, bcur, pairBuf, E);
    }
    k_bucketScan<<<1, NBMAX, 0, stream>>>(bcur, bbase, rowPtr, N, E, NB);
    k_passB<<<NB, B, 0, stream>>>(bcur, bbase, pairBuf, rowPtr, dis, srcIdx, N);

    // ---- node encoder ----
    k_node_init<<<(N * 32 + B - 1) / B, B, 0, stream>>>(x, w_node, b_node, hA, N);

    // ---- layer 1 (K=32) ----
    k_xw<32><<<(N * 64 + B - 1) / B, B, 0, stream>>>(hA, w1, dis, y, N);
    k_agg<false><<<(N * 64 + B - 1) / B, B, 0, stream>>>(rowPtr, srcIdx, y, dis, b1,
                                                         hA, nullptr, nullptr, nullptr, N);

    // ---- layer 2 (K=64) + fused mean-pool accumulate ----
    k_xw<64><<<(N * 64 + B - 1) / B, B, 0, stream>>>(hA, w2, dis, y, N);
    k_agg<true><<<(N * 64 + B - 1) / B, B, 0, stream>>>(rowPtr, srcIdx, y, dis, b2,
                                                        nullptr, batch, sums, cnt, N);

    // ---- head ----
    k_head<<<G, 64, 0, stream>>>(sums, cnt, wf1, bf1, wf2, bf2, out);
}

// Round 5
// 487.216 us; speedup vs baseline: 3.8321x; 1.1400x over previous
//
#include <hip/hip_runtime.h>

// ---------------------------------------------------------------------------
// GNN_20237885899323: 2-layer GCN + mean-pool + MLP head, all fp32.
// Round 5:
//  (a) aggregate-before-matmul: GCN's sum commutes with @W, so gather the
//      pre-scaled h~ = dis*h rows and apply W after. Layer-1 gathers 128 B
//      rows (halved volume, 12.8 MB working set).
//  (b) k_agg restructured: lane = float4 of features, wave covers 4 (F=64) or
//      8 (F=32) rows per load instruction, ~16 rows (4 KB) in flight per wave
//      vs 2 KB before; shfl_xor rowgroup reduce at the end.
// z[v] = dis[v]*(h~[v] + sum_src h~[src]);  h_next~ = dis*relu(z@W + b).
// ---------------------------------------------------------------------------

#define NBMAX 512   // allocated buckets (actual NB = ceil(N/256) = 391)
#define BCAP 12288  // pairBuf capacity per bucket (expected ~8192 +- 90)
#define CAPL 10240  // LDS staging capacity in pass B (40 KB)

__global__ void k_initcur(int* __restrict__ bcur) {
    bcur[threadIdx.x] = threadIdx.x * BCAP;  // 512 threads
}

// pass A: bin edges by dst>>8 into pairBuf regions; entry = (dst&255)<<24 | src
__global__ void k_passA(const int* __restrict__ ei, int* __restrict__ bcur,
                        unsigned int* __restrict__ pairBuf, int E) {
    __shared__ int h[NBMAX];     // hist, then local cursor
    __shared__ int base[NBMAX];  // reserved global base per bucket
    const int T = 256, EPT = 32;
    int chunk = blockIdx.x * (T * EPT);
    int t = threadIdx.x;
    h[t] = 0; h[t + 256] = 0;
    __syncthreads();
    int nE = min(E - chunk, T * EPT);
    for (int i = t; i < nE; i += T)
        atomicAdd(&h[ei[E + chunk + i] >> 8], 1);
    __syncthreads();
    for (int bb = t; bb < NBMAX; bb += T) {
        int c = h[bb];
        base[bb] = c > 0 ? atomicAdd(&bcur[bb], c) : 0;
        h[bb] = 0;  // becomes local cursor
    }
    __syncthreads();
    for (int i = t; i < nE; i += T) {
        int s = ei[chunk + i];
        int d = ei[E + chunk + i];
        int bb = d >> 8;
        int pos = base[bb] + atomicAdd(&h[bb], 1);
        pairBuf[pos] = ((unsigned int)(d & 255) << 24) | (unsigned int)s;
    }
}

// bucket totals -> exclusive scan -> bucketBase; rowPtr[N] = E
__global__ void k_bucketScan(const int* __restrict__ bcur, int* __restrict__ bucketBase,
                             int* __restrict__ rowPtr, int N, int E, int NB) {
    __shared__ int sh[NBMAX];
    int t = threadIdx.x;  // 512
    int c = (t < NB) ? (bcur[t] - t * BCAP) : 0;
    sh[t] = c;
    __syncthreads();
    for (int off = 1; off < NBMAX; off <<= 1) {
        int v = (t >= off) ? sh[t - off] : 0;
        __syncthreads();
        sh[t] += v;
        __syncthreads();
    }
    bucketBase[t] = sh[t] - c;  // exclusive prefix
    if (t == 0) rowPtr[N] = E;
}

// pass B: per-bucket local counting sort; emits rowPtr, dis, srcIdx
__global__ void k_passB(const int* __restrict__ bcur, const int* __restrict__ bucketBase,
                        const unsigned int* __restrict__ pairBuf, int* __restrict__ rowPtr,
                        float* __restrict__ dis, int* __restrict__ srcIdx, int N) {
    __shared__ unsigned int eLds[CAPL];
    __shared__ int hist[256];
    __shared__ int scan[256];
    int b = blockIdx.x;
    int t = threadIdx.x;  // 256
    int count = bcur[b] - b * BCAP;
    int gbase = bucketBase[b];
    const unsigned int* src = pairBuf + (size_t)b * BCAP;
    hist[t] = 0;
    int nStage = min(count, CAPL);
    for (int i = t; i < nStage; i += 256) eLds[i] = src[i];
    __syncthreads();
    for (int i = t; i < nStage; i += 256) atomicAdd(&hist[eLds[i] >> 24], 1);
    for (int i = CAPL + t; i < count; i += 256) atomicAdd(&hist[src[i] >> 24], 1);
    __syncthreads();
    int c = hist[t];
    scan[t] = c;
    __syncthreads();
    for (int off = 1; off < 256; off <<= 1) {
        int v = (t >= off) ? scan[t - off] : 0;
        __syncthreads();
        scan[t] += v;
        __syncthreads();
    }
    int excl = scan[t] - c;
    int node = (b << 8) + t;
    if (node < N) {
        rowPtr[node] = gbase + excl;
        dis[node] = rsqrtf((float)c + 1.0f);  // +1 self loop
    }
    hist[t] = excl;  // reuse as cursor
    __syncthreads();
    for (int i = t; i < nStage; i += 256) {
        unsigned int e = eLds[i];
        int pos = atomicAdd(&hist[e >> 24], 1);
        srcIdx[gbase + pos] = (int)(e & 0xFFFFFFu);
    }
    for (int i = CAPL + t; i < count; i += 256) {
        unsigned int e = src[i];
        int pos = atomicAdd(&hist[e >> 24], 1);
        srcIdx[gbase + pos] = (int)(e & 0xFFFFFFu);
    }
}

// h~0 = dis * relu(x @ w_node + b_node); x:[N,2], w:[2,32]
__global__ void k_node_init(const float* __restrict__ x, const float* __restrict__ w,
                            const float* __restrict__ b, const float* __restrict__ dis,
                            float* __restrict__ h0, int N) {
    int tid = blockIdx.x * blockDim.x + threadIdx.x;
    if (tid >= N * 32) return;
    int n = tid >> 5, f = tid & 31;
    float v = x[2 * n] * w[f] + x[2 * n + 1] * w[32 + f] + b[f];
    v = v > 0.f ? v : 0.f;
    h0[tid] = v * dis[n];
}

// one wave per dst node: z[v] = dis[v] * (y[v] + sum_{src} y[src]); rows of F floats.
// lane = float4 of features; wave covers 64*4/F rows per gather instruction.
template <int F>
__global__ void k_agg(const int* __restrict__ rowPtr, const int* __restrict__ srcIdx,
                      const float* __restrict__ y, const float* __restrict__ dis,
                      float* __restrict__ z, int N) {
    constexpr int QF  = F / 4;            // lanes per row (16 or 8)
    constexpr int RPI = 64 / QF;          // rows per instruction (4 or 8)
    constexpr int U   = (F == 64) ? 4 : 2;  // unroll -> 16 rows in flight
    constexpr int CH  = RPI * U;
    int wid = (blockIdx.x * blockDim.x + threadIdx.x) >> 6;  // node id
    if (wid >= N) return;
    int lane = threadIdx.x & 63;
    int q = lane % QF;   // feature quad
    int r = lane / QF;   // row group
    int beg = rowPtr[wid], end = rowPtr[wid + 1];
    const float4* yq = (const float4*)y;
    float4 acc = {0.f, 0.f, 0.f, 0.f};
    if (r == 0) acc = yq[(size_t)wid * QF + q];  // self row
    int cnt = end - beg;
    int nfull = cnt / CH;
    const int* sp = srcIdx + beg + r;
    for (int it = 0; it < nfull; ++it) {
        int s[U];
#pragma unroll
        for (int u = 0; u < U; ++u) s[u] = sp[u * RPI];
#pragma unroll
        for (int u = 0; u < U; ++u) {
            float4 a = yq[(size_t)s[u] * QF + q];
            acc.x += a.x; acc.y += a.y; acc.z += a.z; acc.w += a.w;
        }
        sp += CH;
    }
    for (int i = beg + nfull * CH + r; i < end; i += RPI) {
        float4 a = yq[(size_t)srcIdx[i] * QF + q];
        acc.x += a.x; acc.y += a.y; acc.z += a.z; acc.w += a.w;
    }
    // reduce across row groups (lanes q, q+QF, q+2QF, ...)
#pragma unroll
    for (int m = QF; m < 64; m <<= 1) {
        acc.x += __shfl_xor(acc.x, m);
        acc.y += __shfl_xor(acc.y, m);
        acc.z += __shfl_xor(acc.z, m);
        acc.w += __shfl_xor(acc.w, m);
    }
    if (r == 0) {
        float dv = dis[wid];
        float4 o = {acc.x * dv, acc.y * dv, acc.z * dv, acc.w * dv};
        ((float4*)z)[(size_t)wid * QF + q] = o;
    }
}

// out = relu(z @ w + b); SCALE: *= dis (next-layer pre-scale);
// POOL: atomicAdd into per-graph sums instead of storing.
template <int KIN, bool SCALE, bool POOL>
__global__ void k_mm(const float* __restrict__ z, const float* __restrict__ w,
                     const float* __restrict__ b, const float* __restrict__ dis,
                     float* __restrict__ hOut, const int* __restrict__ batch,
                     float* __restrict__ sums, float* __restrict__ cnt, int N) {
    int tid = blockIdx.x * blockDim.x + threadIdx.x;
    if (tid >= N * 64) return;
    int n = tid >> 6, f = tid & 63;
    const float* zr = z + (size_t)n * KIN;
    float s = b[f];
#pragma unroll
    for (int k = 0; k < KIN; ++k) s += zr[k] * w[k * 64 + f];
    s = s > 0.f ? s : 0.f;
    if (SCALE) s *= dis[n];
    if (!POOL) {
        hOut[tid] = s;
    } else {
        int g = batch[n];
        atomicAdd(&sums[g * 64 + f], s);
        if (f == 0) atomicAdd(&cnt[g], 1.0f);
    }
}

// per-graph head: pooled -> relu(pooled@wf1+bf1) -> @wf2+bf2
__global__ void k_head(const float* __restrict__ sums, const float* __restrict__ cnt,
                       const float* __restrict__ wf1, const float* __restrict__ bf1,
                       const float* __restrict__ wf2, const float* __restrict__ bf2,
                       float* __restrict__ out) {
    int g = blockIdx.x;
    int t = threadIdx.x;  // 64 threads
    __shared__ float pooled[64];
    __shared__ float gv[32];
    float c = cnt[g];
    c = c > 1.f ? c : 1.f;
    pooled[t] = sums[g * 64 + t] / c;
    __syncthreads();
    if (t < 32) {
        float s = bf1[t];
#pragma unroll
        for (int k = 0; k < 64; ++k) s += pooled[k] * wf1[k * 32 + t];
        gv[t] = s > 0.f ? s : 0.f;
    }
    __syncthreads();
    if (t == 0) {
        float s = bf2[0];
#pragma unroll
        for (int j = 0; j < 32; ++j) s += gv[j] * wf2[j];
        out[g] = s;
    }
}

extern "C" void kernel_launch(void* const* d_in, const int* in_sizes, int n_in,
                              void* d_out, int out_size, void* d_ws, size_t ws_size,
                              hipStream_t stream) {
    const float* x      = (const float*)d_in[0];
    const int*   ei     = (const int*)d_in[2];
    const int*   batch  = (const int*)d_in[3];
    const float* w_node = (const float*)d_in[4];
    const float* b_node = (const float*)d_in[5];
    const float* w1  = (const float*)d_in[8];
    const float* b1  = (const float*)d_in[9];
    const float* w2  = (const float*)d_in[10];
    const float* b2  = (const float*)d_in[11];
    const float* wf1 = (const float*)d_in[12];
    const float* bf1 = (const float*)d_in[13];
    const float* wf2 = (const float*)d_in[14];
    const float* bf2 = (const float*)d_in[15];
    float* out = (float*)d_out;

    const int N = in_sizes[0] / 2;  // 100000
    const int E = in_sizes[2] / 2;  // 3200000
    const int G = out_size;         // 1024
    const int NB = (N + 255) >> 8;  // 391 buckets

    auto align256 = [](size_t v) { return (v + 255) & ~(size_t)255; };
    char* ws = (char*)d_ws;
    size_t off = 0;
    float* dis     = (float*)(ws + off); off += align256((size_t)N * 4);
    int*   rowPtr  = (int*)(ws + off);   off += align256((size_t)(N + 1) * 4);
    int*   bcur    = (int*)(ws + off);   off += align256((size_t)NBMAX * 4);
    int*   bbase   = (int*)(ws + off);   off += align256((size_t)NBMAX * 4);
    int*   srcIdx  = (int*)(ws + off);   off += align256((size_t)E * 4);
    // region1 (25.6 MB): pairBuf during CSR build; then h~0 [N,32] + z [N,32];
    // then z2 [N,64] overwrites both (all dead by then).
    float* region1 = (float*)(ws + off); off += align256((size_t)N * 64 * 4);
    float* hT1     = (float*)(ws + off); off += align256((size_t)N * 64 * 4);  // h~1 [N,64]
    float* sums    = (float*)(ws + off); off += align256((size_t)G * 64 * 4);
    float* cnt     = (float*)(ws + off); off += align256((size_t)G * 4);

    unsigned int* pairBuf = (unsigned int*)region1;  // NB*BCAP*4 = 19.2 MB < 25.6 MB
    float* hT0 = region1;                // [N,32] 12.8 MB
    float* z1  = region1 + (size_t)N * 32;  // [N,32] 12.8 MB
    float* z2  = region1;                // [N,64] 25.6 MB (hT0,z1 dead)

    hipMemsetAsync(sums, 0, (size_t)G * 64 * 4, stream);
    hipMemsetAsync(cnt, 0, (size_t)G * 4, stream);

    const int B = 256;

    // ---- CSR build ----
    k_initcur<<<1, NBMAX, 0, stream>>>(bcur);
    {
        int nblk = (E + B * 32 - 1) / (B * 32);  // 391
        k_passA<<<nblk, B, 0, stream>>>(ei, bcur, pairBuf, E);
    }
    k_bucketScan<<<1, NBMAX, 0, stream>>>(bcur, bbase, rowPtr, N, E, NB);
    k_passB<<<NB, B, 0, stream>>>(bcur, bbase, pairBuf, rowPtr, dis, srcIdx, N);

    // ---- node encoder (pairBuf dead from here) ----
    k_node_init<<<(N * 32 + B - 1) / B, B, 0, stream>>>(x, w_node, b_node, dis, hT0, N);

    // ---- layer 1: aggregate h~0 (128 B rows), then z1 @ w1 -> h~1 ----
    k_agg<32><<<(N * 64 + B - 1) / B, B, 0, stream>>>(rowPtr, srcIdx, hT0, dis, z1, N);
    k_mm<32, true, false><<<(N * 64 + B - 1) / B, B, 0, stream>>>(
        z1, w1, b1, dis, hT1, nullptr, nullptr, nullptr, N);

    // ---- layer 2: aggregate h~1 (256 B rows), then z2 @ w2 + fused pool ----
    k_agg<64><<<(N * 64 + B - 1) / B, B, 0, stream>>>(rowPtr, srcIdx, hT1, dis, z2, N);
    k_mm<64, false, true><<<(N * 64 + B - 1) / B, B, 0, stream>>>(
        z2, w2, b2, nullptr, nullptr, batch, sums, cnt, N);

    // ---- head ----
    k_head<<<G, 64, 0, stream>>>(sums, cnt, wf1, bf1, wf2, bf2, out);
}

// Round 6
// 349.770 us; speedup vs baseline: 5.3380x; 1.3930x over previous
//
#include <hip/hip_runtime.h>

// ---------------------------------------------------------------------------
// GNN_20237885899323: 2-layer GCN + mean-pool + MLP head, all fp32.
// Round 6: round-5 found k_mm<64,fused-pool> burning ~230us on memory-side
// atomic drain (6.4M fp32 atomics into 256KB of sorted-batch graph sums,
// nothing to hide the drain behind). Fix: batch is sorted -> block-per-graph
// k_poolhead binary-searches its node range, computes h2=relu(z2@w2+b2) on
// the fly, register/LDS mean, fused MLP head. Zero pool atomics; k_mm<64>,
// k_head, sums/cnt buffers and memsets all eliminated.
// ---------------------------------------------------------------------------

#define NBMAX 512   // allocated buckets (actual NB = ceil(N/256) = 391)
#define BCAP 12288  // pairBuf capacity per bucket (expected ~8192 +- 90)
#define CAPL 10240  // LDS staging capacity in pass B (40 KB)

__global__ void k_initcur(int* __restrict__ bcur) {
    bcur[threadIdx.x] = threadIdx.x * BCAP;  // 512 threads
}

// pass A: bin edges by dst>>8 into pairBuf regions; entry = (dst&255)<<24 | src
__global__ void k_passA(const int* __restrict__ ei, int* __restrict__ bcur,
                        unsigned int* __restrict__ pairBuf, int E) {
    __shared__ int h[NBMAX];     // hist, then local cursor
    __shared__ int base[NBMAX];  // reserved global base per bucket
    const int T = 256, EPT = 32;
    int chunk = blockIdx.x * (T * EPT);
    int t = threadIdx.x;
    h[t] = 0; h[t + 256] = 0;
    __syncthreads();
    int nE = min(E - chunk, T * EPT);
    for (int i = t; i < nE; i += T)
        atomicAdd(&h[ei[E + chunk + i] >> 8], 1);
    __syncthreads();
    for (int bb = t; bb < NBMAX; bb += T) {
        int c = h[bb];
        base[bb] = c > 0 ? atomicAdd(&bcur[bb], c) : 0;
        h[bb] = 0;  // becomes local cursor
    }
    __syncthreads();
    for (int i = t; i < nE; i += T) {
        int s = ei[chunk + i];
        int d = ei[E + chunk + i];
        int bb = d >> 8;
        int pos = base[bb] + atomicAdd(&h[bb], 1);
        pairBuf[pos] = ((unsigned int)(d & 255) << 24) | (unsigned int)s;
    }
}

// bucket totals -> exclusive scan -> bucketBase; rowPtr[N] = E
__global__ void k_bucketScan(const int* __restrict__ bcur, int* __restrict__ bucketBase,
                             int* __restrict__ rowPtr, int N, int E, int NB) {
    __shared__ int sh[NBMAX];
    int t = threadIdx.x;  // 512
    int c = (t < NB) ? (bcur[t] - t * BCAP) : 0;
    sh[t] = c;
    __syncthreads();
    for (int off = 1; off < NBMAX; off <<= 1) {
        int v = (t >= off) ? sh[t - off] : 0;
        __syncthreads();
        sh[t] += v;
        __syncthreads();
    }
    bucketBase[t] = sh[t] - c;  // exclusive prefix
    if (t == 0) rowPtr[N] = E;
}

// pass B: per-bucket local counting sort; emits rowPtr, dis, srcIdx
__global__ void k_passB(const int* __restrict__ bcur, const int* __restrict__ bucketBase,
                        const unsigned int* __restrict__ pairBuf, int* __restrict__ rowPtr,
                        float* __restrict__ dis, int* __restrict__ srcIdx, int N) {
    __shared__ unsigned int eLds[CAPL];
    __shared__ int hist[256];
    __shared__ int scan[256];
    int b = blockIdx.x;
    int t = threadIdx.x;  // 256
    int count = bcur[b] - b * BCAP;
    int gbase = bucketBase[b];
    const unsigned int* src = pairBuf + (size_t)b * BCAP;
    hist[t] = 0;
    int nStage = min(count, CAPL);
    for (int i = t; i < nStage; i += 256) eLds[i] = src[i];
    __syncthreads();
    for (int i = t; i < nStage; i += 256) atomicAdd(&hist[eLds[i] >> 24], 1);
    for (int i = CAPL + t; i < count; i += 256) atomicAdd(&hist[src[i] >> 24], 1);
    __syncthreads();
    int c = hist[t];
    scan[t] = c;
    __syncthreads();
    for (int off = 1; off < 256; off <<= 1) {
        int v = (t >= off) ? scan[t - off] : 0;
        __syncthreads();
        scan[t] += v;
        __syncthreads();
    }
    int excl = scan[t] - c;
    int node = (b << 8) + t;
    if (node < N) {
        rowPtr[node] = gbase + excl;
        dis[node] = rsqrtf((float)c + 1.0f);  // +1 self loop
    }
    hist[t] = excl;  // reuse as cursor
    __syncthreads();
    for (int i = t; i < nStage; i += 256) {
        unsigned int e = eLds[i];
        int pos = atomicAdd(&hist[e >> 24], 1);
        srcIdx[gbase + pos] = (int)(e & 0xFFFFFFu);
    }
    for (int i = CAPL + t; i < count; i += 256) {
        unsigned int e = src[i];
        int pos = atomicAdd(&hist[e >> 24], 1);
        srcIdx[gbase + pos] = (int)(e & 0xFFFFFFu);
    }
}

// h~0 = dis * relu(x @ w_node + b_node); x:[N,2], w:[2,32]
__global__ void k_node_init(const float* __restrict__ x, const float* __restrict__ w,
                            const float* __restrict__ b, const float* __restrict__ dis,
                            float* __restrict__ h0, int N) {
    int tid = blockIdx.x * blockDim.x + threadIdx.x;
    if (tid >= N * 32) return;
    int n = tid >> 5, f = tid & 31;
    float v = x[2 * n] * w[f] + x[2 * n + 1] * w[32 + f] + b[f];
    v = v > 0.f ? v : 0.f;
    h0[tid] = v * dis[n];
}

// one wave per dst node: z[v] = dis[v] * (y[v] + sum_{src} y[src]); rows of F floats.
// lane = float4 of features; wave covers 64*4/F rows per gather instruction.
template <int F>
__global__ void k_agg(const int* __restrict__ rowPtr, const int* __restrict__ srcIdx,
                      const float* __restrict__ y, const float* __restrict__ dis,
                      float* __restrict__ z, int N) {
    constexpr int QF  = F / 4;              // lanes per row (16 or 8)
    constexpr int RPI = 64 / QF;            // rows per instruction (4 or 8)
    constexpr int U   = (F == 64) ? 4 : 2;  // unroll -> 16 rows in flight
    constexpr int CH  = RPI * U;
    int wid = (blockIdx.x * blockDim.x + threadIdx.x) >> 6;  // node id
    if (wid >= N) return;
    int lane = threadIdx.x & 63;
    int q = lane % QF;   // feature quad
    int r = lane / QF;   // row group
    int beg = rowPtr[wid], end = rowPtr[wid + 1];
    const float4* yq = (const float4*)y;
    float4 acc = {0.f, 0.f, 0.f, 0.f};
    if (r == 0) acc = yq[(size_t)wid * QF + q];  // self row
    int cnt = end - beg;
    int nfull = cnt / CH;
    const int* sp = srcIdx + beg + r;
    for (int it = 0; it < nfull; ++it) {
        int s[U];
#pragma unroll
        for (int u = 0; u < U; ++u) s[u] = sp[u * RPI];
#pragma unroll
        for (int u = 0; u < U; ++u) {
            float4 a = yq[(size_t)s[u] * QF + q];
            acc.x += a.x; acc.y += a.y; acc.z += a.z; acc.w += a.w;
        }
        sp += CH;
    }
    for (int i = beg + nfull * CH + r; i < end; i += RPI) {
        float4 a = yq[(size_t)srcIdx[i] * QF + q];
        acc.x += a.x; acc.y += a.y; acc.z += a.z; acc.w += a.w;
    }
    // reduce across row groups (lanes q, q+QF, q+2QF, ...)
#pragma unroll
    for (int m = QF; m < 64; m <<= 1) {
        acc.x += __shfl_xor(acc.x, m);
        acc.y += __shfl_xor(acc.y, m);
        acc.z += __shfl_xor(acc.z, m);
        acc.w += __shfl_xor(acc.w, m);
    }
    if (r == 0) {
        float dv = dis[wid];
        float4 o = {acc.x * dv, acc.y * dv, acc.z * dv, acc.w * dv};
        ((float4*)z)[(size_t)wid * QF + q] = o;
    }
}

// h~1 = dis * relu(z1 @ w1 + b1); z1:[N,32], w1:[32,64]
__global__ void k_mm32(const float* __restrict__ z, const float* __restrict__ w,
                       const float* __restrict__ b, const float* __restrict__ dis,
                       float* __restrict__ hOut, int N) {
    int tid = blockIdx.x * blockDim.x + threadIdx.x;
    if (tid >= N * 64) return;
    int n = tid >> 6, f = tid & 63;
    const float4* zr = (const float4*)(z + (size_t)n * 32);
    float s = b[f];
#pragma unroll
    for (int kq = 0; kq < 8; ++kq) {
        float4 zv = zr[kq];
        s += zv.x * w[(4 * kq + 0) * 64 + f];
        s += zv.y * w[(4 * kq + 1) * 64 + f];
        s += zv.z * w[(4 * kq + 2) * 64 + f];
        s += zv.w * w[(4 * kq + 3) * 64 + f];
    }
    s = fmaxf(s, 0.f);
    hOut[tid] = s * dis[n];
}

// block-per-graph: batch is sorted -> binary-search node range [s,e);
// h2[n] = relu(z2[n]@w2 + b2) computed on the fly; pooled mean; MLP head.
__global__ void k_poolhead(const float* __restrict__ z2, const float* __restrict__ w2,
                           const float* __restrict__ b2, const int* __restrict__ batch,
                           const float* __restrict__ wf1, const float* __restrict__ bf1,
                           const float* __restrict__ wf2, const float* __restrict__ bf2,
                           float* __restrict__ out, int N) {
    __shared__ float red[4][64];
    __shared__ float pooled[64];
    __shared__ float gv[32];
    __shared__ int range[2];
    int g = blockIdx.x;
    int t = threadIdx.x;  // 256
    if (t < 2) {
        int target = g + t;  // lower_bound(batch, target)
        int lo = 0, hi = N;
        while (lo < hi) {
            int mid = (lo + hi) >> 1;
            if (batch[mid] < target) lo = mid + 1; else hi = mid;
        }
        range[t] = lo;
    }
    __syncthreads();
    int s = range[0], e = range[1];
    int w = t >> 6, f = t & 63;
    float wcol[64];
#pragma unroll
    for (int k = 0; k < 64; ++k) wcol[k] = w2[k * 64 + f];
    float bf = b2[f];
    float acc = 0.f;
    for (int n = s + w; n < e; n += 4) {
        const float4* zr = (const float4*)(z2 + (size_t)n * 64);
        float h = bf;
#pragma unroll
        for (int kq = 0; kq < 16; ++kq) {
            float4 zv = zr[kq];
            h += zv.x * wcol[4 * kq + 0];
            h += zv.y * wcol[4 * kq + 1];
            h += zv.z * wcol[4 * kq + 2];
            h += zv.w * wcol[4 * kq + 3];
        }
        acc += fmaxf(h, 0.f);
    }
    red[w][f] = acc;
    __syncthreads();
    if (t < 64) {
        float c = (float)(e - s);
        c = c > 1.f ? c : 1.f;
        pooled[t] = (red[0][t] + red[1][t] + red[2][t] + red[3][t]) / c;
    }
    __syncthreads();
    if (t < 32) {
        float sv = bf1[t];
#pragma unroll
        for (int k = 0; k < 64; ++k) sv += pooled[k] * wf1[k * 32 + t];
        gv[t] = fmaxf(sv, 0.f);
    }
    __syncthreads();
    if (t == 0) {
        float sv = bf2[0];
#pragma unroll
        for (int j = 0; j < 32; ++j) sv += gv[j] * wf2[j];
        out[g] = sv;
    }
}

extern "C" void kernel_launch(void* const* d_in, const int* in_sizes, int n_in,
                              void* d_out, int out_size, void* d_ws, size_t ws_size,
                              hipStream_t stream) {
    const float* x      = (const float*)d_in[0];
    const int*   ei     = (const int*)d_in[2];
    const int*   batch  = (const int*)d_in[3];
    const float* w_node = (const float*)d_in[4];
    const float* b_node = (const float*)d_in[5];
    const float* w1  = (const float*)d_in[8];
    const float* b1  = (const float*)d_in[9];
    const float* w2  = (const float*)d_in[10];
    const float* b2  = (const float*)d_in[11];
    const float* wf1 = (const float*)d_in[12];
    const float* bf1 = (const float*)d_in[13];
    const float* wf2 = (const float*)d_in[14];
    const float* bf2 = (const float*)d_in[15];
    float* out = (float*)d_out;

    const int N = in_sizes[0] / 2;  // 100000
    const int E = in_sizes[2] / 2;  // 3200000
    const int G = out_size;         // 1024
    const int NB = (N + 255) >> 8;  // 391 buckets

    auto align256 = [](size_t v) { return (v + 255) & ~(size_t)255; };
    char* ws = (char*)d_ws;
    size_t off = 0;
    float* dis     = (float*)(ws + off); off += align256((size_t)N * 4);
    int*   rowPtr  = (int*)(ws + off);   off += align256((size_t)(N + 1) * 4);
    int*   bcur    = (int*)(ws + off);   off += align256((size_t)NBMAX * 4);
    int*   bbase   = (int*)(ws + off);   off += align256((size_t)NBMAX * 4);
    int*   srcIdx  = (int*)(ws + off);   off += align256((size_t)E * 4);
    // region1 (25.6 MB): pairBuf during CSR build; then h~0 [N,32] + z1 [N,32];
    // then z2 [N,64] overwrites both (dead by then).
    float* region1 = (float*)(ws + off); off += align256((size_t)N * 64 * 4);
    float* hT1     = (float*)(ws + off); off += align256((size_t)N * 64 * 4);  // h~1 [N,64]

    unsigned int* pairBuf = (unsigned int*)region1;  // NB*BCAP*4 = 19.2 MB < 25.6 MB
    float* hT0 = region1;                   // [N,32] 12.8 MB
    float* z1  = region1 + (size_t)N * 32;  // [N,32] 12.8 MB
    float* z2  = region1;                   // [N,64] 25.6 MB (hT0,z1 dead)

    const int B = 256;

    // ---- CSR build ----
    k_initcur<<<1, NBMAX, 0, stream>>>(bcur);
    {
        int nblk = (E + B * 32 - 1) / (B * 32);  // 391
        k_passA<<<nblk, B, 0, stream>>>(ei, bcur, pairBuf, E);
    }
    k_bucketScan<<<1, NBMAX, 0, stream>>>(bcur, bbase, rowPtr, N, E, NB);
    k_passB<<<NB, B, 0, stream>>>(bcur, bbase, pairBuf, rowPtr, dis, srcIdx, N);

    // ---- node encoder (pairBuf dead from here) ----
    k_node_init<<<(N * 32 + B - 1) / B, B, 0, stream>>>(x, w_node, b_node, dis, hT0, N);

    // ---- layer 1: aggregate h~0 (128 B rows), then z1 @ w1 -> h~1 ----
    k_agg<32><<<(N * 64 + B - 1) / B, B, 0, stream>>>(rowPtr, srcIdx, hT0, dis, z1, N);
    k_mm32<<<(N * 64 + B - 1) / B, B, 0, stream>>>(z1, w1, b1, dis, hT1, N);

    // ---- layer 2: aggregate h~1 (256 B rows) -> z2 ----
    k_agg<64><<<(N * 64 + B - 1) / B, B, 0, stream>>>(rowPtr, srcIdx, hT1, dis, z2, N);

    // ---- fused h2-compute + mean-pool + head (block per graph, no atomics) ----
    k_poolhead<<<G, B, 0, stream>>>(z2, w2, b2, batch, wf1, bf1, wf2, bf2, out, N);
}

// Round 7
// 303.227 us; speedup vs baseline: 6.1573x; 1.1535x over previous
//
#include <hip/hip_runtime.h>

// ---------------------------------------------------------------------------
// GNN_20237885899323: 2-layer GCN + mean-pool + MLP head, all fp32.
// Round 7:
//  (a) k_agg: masked deep-unroll gather (U=8 for F=64) — old code issued one
//      8-deep burst then a SERIAL tail (deg~Poisson(32)); now every iteration
//      keeps 8 float4 gathers in flight (OOB clamped to last row, FMA-masked).
//      A/B on whether the 3.75 TB/s L2-miss stream is latency- or BW-bound.
//  (b) k_agg32mm: layer-1 matmul fused into the aggregation epilogue via
//      shfl-broadcast (butterfly all-reduce leaves full z-quad in every lane);
//      kills k_mm32 dispatch + the 25.6 MB z1 round-trip.
// ---------------------------------------------------------------------------

#define NBMAX 512   // allocated buckets (actual NB = ceil(N/256) = 391)
#define BCAP 12288  // pairBuf capacity per bucket (expected ~8192 +- 90)
#define CAPL 10240  // LDS staging capacity in pass B (40 KB)

__global__ void k_initcur(int* __restrict__ bcur) {
    bcur[threadIdx.x] = threadIdx.x * BCAP;  // 512 threads
}

// pass A: bin edges by dst>>8 into pairBuf regions; entry = (dst&255)<<24 | src
__global__ void k_passA(const int* __restrict__ ei, int* __restrict__ bcur,
                        unsigned int* __restrict__ pairBuf, int E) {
    __shared__ int h[NBMAX];     // hist, then local cursor
    __shared__ int base[NBMAX];  // reserved global base per bucket
    const int T = 256, EPT = 32;
    int chunk = blockIdx.x * (T * EPT);
    int t = threadIdx.x;
    h[t] = 0; h[t + 256] = 0;
    __syncthreads();
    int nE = min(E - chunk, T * EPT);
    for (int i = t; i < nE; i += T)
        atomicAdd(&h[ei[E + chunk + i] >> 8], 1);
    __syncthreads();
    for (int bb = t; bb < NBMAX; bb += T) {
        int c = h[bb];
        base[bb] = c > 0 ? atomicAdd(&bcur[bb], c) : 0;
        h[bb] = 0;  // becomes local cursor
    }
    __syncthreads();
    for (int i = t; i < nE; i += T) {
        int s = ei[chunk + i];
        int d = ei[E + chunk + i];
        int bb = d >> 8;
        int pos = base[bb] + atomicAdd(&h[bb], 1);
        pairBuf[pos] = ((unsigned int)(d & 255) << 24) | (unsigned int)s;
    }
}

// bucket totals -> exclusive scan -> bucketBase; rowPtr[N] = E
__global__ void k_bucketScan(const int* __restrict__ bcur, int* __restrict__ bucketBase,
                             int* __restrict__ rowPtr, int N, int E, int NB) {
    __shared__ int sh[NBMAX];
    int t = threadIdx.x;  // 512
    int c = (t < NB) ? (bcur[t] - t * BCAP) : 0;
    sh[t] = c;
    __syncthreads();
    for (int off = 1; off < NBMAX; off <<= 1) {
        int v = (t >= off) ? sh[t - off] : 0;
        __syncthreads();
        sh[t] += v;
        __syncthreads();
    }
    bucketBase[t] = sh[t] - c;  // exclusive prefix
    if (t == 0) rowPtr[N] = E;
}

// pass B: per-bucket local counting sort; emits rowPtr, dis, srcIdx
__global__ void k_passB(const int* __restrict__ bcur, const int* __restrict__ bucketBase,
                        const unsigned int* __restrict__ pairBuf, int* __restrict__ rowPtr,
                        float* __restrict__ dis, int* __restrict__ srcIdx, int N) {
    __shared__ unsigned int eLds[CAPL];
    __shared__ int hist[256];
    __shared__ int scan[256];
    int b = blockIdx.x;
    int t = threadIdx.x;  // 256
    int count = bcur[b] - b * BCAP;
    int gbase = bucketBase[b];
    const unsigned int* src = pairBuf + (size_t)b * BCAP;
    hist[t] = 0;
    int nStage = min(count, CAPL);
    for (int i = t; i < nStage; i += 256) eLds[i] = src[i];
    __syncthreads();
    for (int i = t; i < nStage; i += 256) atomicAdd(&hist[eLds[i] >> 24], 1);
    for (int i = CAPL + t; i < count; i += 256) atomicAdd(&hist[src[i] >> 24], 1);
    __syncthreads();
    int c = hist[t];
    scan[t] = c;
    __syncthreads();
    for (int off = 1; off < 256; off <<= 1) {
        int v = (t >= off) ? scan[t - off] : 0;
        __syncthreads();
        scan[t] += v;
        __syncthreads();
    }
    int excl = scan[t] - c;
    int node = (b << 8) + t;
    if (node < N) {
        rowPtr[node] = gbase + excl;
        dis[node] = rsqrtf((float)c + 1.0f);  // +1 self loop
    }
    hist[t] = excl;  // reuse as cursor
    __syncthreads();
    for (int i = t; i < nStage; i += 256) {
        unsigned int e = eLds[i];
        int pos = atomicAdd(&hist[e >> 24], 1);
        srcIdx[gbase + pos] = (int)(e & 0xFFFFFFu);
    }
    for (int i = CAPL + t; i < count; i += 256) {
        unsigned int e = src[i];
        int pos = atomicAdd(&hist[e >> 24], 1);
        srcIdx[gbase + pos] = (int)(e & 0xFFFFFFu);
    }
}

// h~0 = dis * relu(x @ w_node + b_node); x:[N,2], w:[2,32]
__global__ void k_node_init(const float* __restrict__ x, const float* __restrict__ w,
                            const float* __restrict__ b, const float* __restrict__ dis,
                            float* __restrict__ h0, int N) {
    int tid = blockIdx.x * blockDim.x + threadIdx.x;
    if (tid >= N * 32) return;
    int n = tid >> 5, f = tid & 31;
    float v = x[2 * n] * w[f] + x[2 * n + 1] * w[32 + f] + b[f];
    v = v > 0.f ? v : 0.f;
    h0[tid] = v * dis[n];
}

// layer 2 aggregation: one wave per dst node, rows of 64 floats.
// z[v] = dis[v] * (y[v] + sum_src y[src]). Masked deep-unroll: 8 float4
// gathers in flight every iteration; OOB clamps to last row, FMA-masked.
__global__ void k_agg64(const int* __restrict__ rowPtr, const int* __restrict__ srcIdx,
                        const float* __restrict__ y, const float* __restrict__ dis,
                        float* __restrict__ z, int N) {
    constexpr int QF = 16, RPI = 4, U = 8, CH = RPI * U;  // 32 rows per iter
    int wid = (blockIdx.x * blockDim.x + threadIdx.x) >> 6;
    if (wid >= N) return;
    int lane = threadIdx.x & 63;
    int q = lane & (QF - 1);  // feature quad
    int r = lane / QF;        // row group 0..3
    int beg = rowPtr[wid], end = rowPtr[wid + 1];
    const float4* yq = (const float4*)y;
    float4 acc = {0.f, 0.f, 0.f, 0.f};
    if (r == 0) acc = yq[(size_t)wid * QF + q];  // self row
    if (end > beg) {
        int last = end - 1;
        for (int base = beg; base < end; base += CH) {
            int s[U];
            float m[U];
#pragma unroll
            for (int u = 0; u < U; ++u) {
                int i = base + r + u * RPI;
                m[u] = (i < end) ? 1.f : 0.f;
                s[u] = srcIdx[min(i, last)];
            }
#pragma unroll
            for (int u = 0; u < U; ++u) {
                float4 a = yq[(size_t)s[u] * QF + q];
                acc.x = fmaf(a.x, m[u], acc.x);
                acc.y = fmaf(a.y, m[u], acc.y);
                acc.z = fmaf(a.z, m[u], acc.z);
                acc.w = fmaf(a.w, m[u], acc.w);
            }
        }
    }
#pragma unroll
    for (int mk = QF; mk < 64; mk <<= 1) {
        acc.x += __shfl_xor(acc.x, mk);
        acc.y += __shfl_xor(acc.y, mk);
        acc.z += __shfl_xor(acc.z, mk);
        acc.w += __shfl_xor(acc.w, mk);
    }
    if (r == 0) {
        float dv = dis[wid];
        float4 o = {acc.x * dv, acc.y * dv, acc.z * dv, acc.w * dv};
        ((float4*)z)[(size_t)wid * QF + q] = o;
    }
}

// layer 1 aggregation + fused matmul: one wave per dst node, rows of 32 floats.
// agg = y0[v] + sum_src y0[src]  (butterfly all-reduce -> every lane has the
// full quad for q=lane&7); then h~1[v][f] = dis*relu(dis*(agg@w1)+b1) via
// shfl-broadcast of the 32 agg values. Kills the z1 round-trip + k_mm32.
__global__ void k_agg32mm(const int* __restrict__ rowPtr, const int* __restrict__ srcIdx,
                          const float* __restrict__ y, const float* __restrict__ dis,
                          const float* __restrict__ w1, const float* __restrict__ b1,
                          float* __restrict__ hOut, int N) {
    constexpr int QF = 8, RPI = 8, U = 4, CH = RPI * U;  // 32 rows per iter
    int wid = (blockIdx.x * blockDim.x + threadIdx.x) >> 6;
    if (wid >= N) return;
    int lane = threadIdx.x & 63;
    int q = lane & (QF - 1);
    int r = lane / QF;  // 0..7
    int beg = rowPtr[wid], end = rowPtr[wid + 1];
    const float4* yq = (const float4*)y;
    float4 acc = {0.f, 0.f, 0.f, 0.f};
    if (r == 0) acc = yq[(size_t)wid * QF + q];  // self row
    if (end > beg) {
        int last = end - 1;
        for (int base = beg; base < end; base += CH) {
            int s[U];
            float m[U];
#pragma unroll
            for (int u = 0; u < U; ++u) {
                int i = base + r + u * RPI;
                m[u] = (i < end) ? 1.f : 0.f;
                s[u] = srcIdx[min(i, last)];
            }
#pragma unroll
            for (int u = 0; u < U; ++u) {
                float4 a = yq[(size_t)s[u] * QF + q];
                acc.x = fmaf(a.x, m[u], acc.x);
                acc.y = fmaf(a.y, m[u], acc.y);
                acc.z = fmaf(a.z, m[u], acc.z);
                acc.w = fmaf(a.w, m[u], acc.w);
            }
        }
    }
#pragma unroll
    for (int mk = QF; mk < 64; mk <<= 1) {
        acc.x += __shfl_xor(acc.x, mk);
        acc.y += __shfl_xor(acc.y, mk);
        acc.z += __shfl_xor(acc.z, mk);
        acc.w += __shfl_xor(acc.w, mk);
    }
    // every lane now holds the full agg quad for its q = lane&7.
    // fused matmul: s_raw = agg @ w1 column f (f = lane)
    int f = lane;
    float s = 0.f;
#pragma unroll
    for (int q2 = 0; q2 < QF; ++q2) {
        float bx = __shfl(acc.x, q2);
        float by = __shfl(acc.y, q2);
        float bz = __shfl(acc.z, q2);
        float bw = __shfl(acc.w, q2);
        s = fmaf(bx, w1[(4 * q2 + 0) * 64 + f], s);
        s = fmaf(by, w1[(4 * q2 + 1) * 64 + f], s);
        s = fmaf(bz, w1[(4 * q2 + 2) * 64 + f], s);
        s = fmaf(bw, w1[(4 * q2 + 3) * 64 + f], s);
    }
    float dv = dis[wid];
    float h = fmaxf(fmaf(dv, s, b1[f]), 0.f) * dv;  // dis*relu(dis*s_raw + b1)
    hOut[(size_t)wid * 64 + f] = h;
}

// block-per-graph: batch is sorted -> binary-search node range [s,e);
// h2[n] = relu(z2[n]@w2 + b2) computed on the fly; pooled mean; MLP head.
__global__ void k_poolhead(const float* __restrict__ z2, const float* __restrict__ w2,
                           const float* __restrict__ b2, const int* __restrict__ batch,
                           const float* __restrict__ wf1, const float* __restrict__ bf1,
                           const float* __restrict__ wf2, const float* __restrict__ bf2,
                           float* __restrict__ out, int N) {
    __shared__ float red[4][64];
    __shared__ float pooled[64];
    __shared__ float gv[32];
    __shared__ int range[2];
    int g = blockIdx.x;
    int t = threadIdx.x;  // 256
    if (t < 2) {
        int target = g + t;  // lower_bound(batch, target)
        int lo = 0, hi = N;
        while (lo < hi) {
            int mid = (lo + hi) >> 1;
            if (batch[mid] < target) lo = mid + 1; else hi = mid;
        }
        range[t] = lo;
    }
    __syncthreads();
    int s = range[0], e = range[1];
    int w = t >> 6, f = t & 63;
    float wcol[64];
#pragma unroll
    for (int k = 0; k < 64; ++k) wcol[k] = w2[k * 64 + f];
    float bf = b2[f];
    float acc = 0.f;
    for (int n = s + w; n < e; n += 4) {
        const float4* zr = (const float4*)(z2 + (size_t)n * 64);
        float h = bf;
#pragma unroll
        for (int kq = 0; kq < 16; ++kq) {
            float4 zv = zr[kq];
            h += zv.x * wcol[4 * kq + 0];
            h += zv.y * wcol[4 * kq + 1];
            h += zv.z * wcol[4 * kq + 2];
            h += zv.w * wcol[4 * kq + 3];
        }
        acc += fmaxf(h, 0.f);
    }
    red[w][f] = acc;
    __syncthreads();
    if (t < 64) {
        float c = (float)(e - s);
        c = c > 1.f ? c : 1.f;
        pooled[t] = (red[0][t] + red[1][t] + red[2][t] + red[3][t]) / c;
    }
    __syncthreads();
    if (t < 32) {
        float sv = bf1[t];
#pragma unroll
        for (int k = 0; k < 64; ++k) sv += pooled[k] * wf1[k * 32 + t];
        gv[t] = fmaxf(sv, 0.f);
    }
    __syncthreads();
    if (t == 0) {
        float sv = bf2[0];
#pragma unroll
        for (int j = 0; j < 32; ++j) sv += gv[j] * wf2[j];
        out[g] = sv;
    }
}

extern "C" void kernel_launch(void* const* d_in, const int* in_sizes, int n_in,
                              void* d_out, int out_size, void* d_ws, size_t ws_size,
                              hipStream_t stream) {
    const float* x      = (const float*)d_in[0];
    const int*   ei     = (const int*)d_in[2];
    const int*   batch  = (const int*)d_in[3];
    const float* w_node = (const float*)d_in[4];
    const float* b_node = (const float*)d_in[5];
    const float* w1  = (const float*)d_in[8];
    const float* b1  = (const float*)d_in[9];
    const float* w2  = (const float*)d_in[10];
    const float* b2  = (const float*)d_in[11];
    const float* wf1 = (const float*)d_in[12];
    const float* bf1 = (const float*)d_in[13];
    const float* wf2 = (const float*)d_in[14];
    const float* bf2 = (const float*)d_in[15];
    float* out = (float*)d_out;

    const int N = in_sizes[0] / 2;  // 100000
    const int E = in_sizes[2] / 2;  // 3200000
    const int G = out_size;         // 1024
    const int NB = (N + 255) >> 8;  // 391 buckets

    auto align256 = [](size_t v) { return (v + 255) & ~(size_t)255; };
    char* ws = (char*)d_ws;
    size_t off = 0;
    float* dis     = (float*)(ws + off); off += align256((size_t)N * 4);
    int*   rowPtr  = (int*)(ws + off);   off += align256((size_t)(N + 1) * 4);
    int*   bcur    = (int*)(ws + off);   off += align256((size_t)NBMAX * 4);
    int*   bbase   = (int*)(ws + off);   off += align256((size_t)NBMAX * 4);
    int*   srcIdx  = (int*)(ws + off);   off += align256((size_t)E * 4);
    // region1 (25.6 MB): pairBuf during CSR build; then h~0 [N,32]; then
    // z2 [N,64] overwrites (h~0 dead by then).
    float* region1 = (float*)(ws + off); off += align256((size_t)N * 64 * 4);
    float* hT1     = (float*)(ws + off); off += align256((size_t)N * 64 * 4);  // h~1 [N,64]

    unsigned int* pairBuf = (unsigned int*)region1;  // NB*BCAP*4 = 19.2 MB < 25.6 MB
    float* hT0 = region1;  // [N,32] 12.8 MB
    float* z2  = region1;  // [N,64] 25.6 MB (hT0 dead by layer 2)

    const int B = 256;

    // ---- CSR build ----
    k_initcur<<<1, NBMAX, 0, stream>>>(bcur);
    {
        int nblk = (E + B * 32 - 1) / (B * 32);  // 391
        k_passA<<<nblk, B, 0, stream>>>(ei, bcur, pairBuf, E);
    }
    k_bucketScan<<<1, NBMAX, 0, stream>>>(bcur, bbase, rowPtr, N, E, NB);
    k_passB<<<NB, B, 0, stream>>>(bcur, bbase, pairBuf, rowPtr, dis, srcIdx, N);

    // ---- node encoder (pairBuf dead from here) ----
    k_node_init<<<(N * 32 + B - 1) / B, B, 0, stream>>>(x, w_node, b_node, dis, hT0, N);

    // ---- layer 1: aggregate h~0 (128 B rows) + fused @w1 -> h~1 ----
    k_agg32mm<<<(N * 64 + B - 1) / B, B, 0, stream>>>(rowPtr, srcIdx, hT0, dis,
                                                      w1, b1, hT1, N);

    // ---- layer 2: aggregate h~1 (256 B rows) -> z2 ----
    k_agg64<<<(N * 64 + B - 1) / B, B, 0, stream>>>(rowPtr, srcIdx, hT1, dis, z2, N);

    // ---- fused h2-compute + mean-pool + head (block per graph, no atomics) ----
    k_poolhead<<<G, B, 0, stream>>>(z2, w2, b2, batch, wf1, bf1, wf2, bf2, out, N);
}